// Round 6
// baseline (7345.448 us; speedup 1.0000x reference)
//
#include <hip/hip_runtime.h>

#define HID 15
#define NG  60      // 4*HID
#define DIM 64
#define SEQT 2048
#define NLAY 4

// Round-to-nearest-even bf16 quantization (bit ops — fast-math-proof).
__device__ __forceinline__ float bfr(float x) {
    unsigned u = __float_as_uint(x);
    u = (u + 0x7FFFu + ((u >> 16) & 1u)) & 0xFFFF0000u;
    return __uint_as_float(u);
}

// one bf16-rounded multiply-accumulate term: acc = bf(acc + bf(a*b))
#define CH(acc, a, b) acc = bfr(acc + bfr((a) * (b)))

// np.tanh(bf16 z): upcast f32, accurate tanh, round once.
// (1-e)/(1+e) with e=exp(-2z): numerator exact by Sterbenz for |z|<0.35.
__device__ __forceinline__ float tanh_np(float z) {
    const float e = __expf(-2.0f * z);
    return bfr((1.0f - e) / (1.0f + e));
}
// np sigmoid: 1/(1+np.exp(-z)) — three separate bf16-rounded ops.
__device__ __forceinline__ float sig_np(float z) {
    const float e   = bfr(__expf(-z));
    const float den = bfr(1.0f + e);
    return bfr(1.0f / den);
}

__global__ __launch_bounds__(64, 1)
void lstm4_bf16np(const float* __restrict__ emb,
                  const int*   __restrict__ lengths,
                  const float* __restrict__ Wih0,
                  const float* __restrict__ Wihr,
                  const float* __restrict__ Whh,
                  const float* __restrict__ bih,
                  const float* __restrict__ bhh,
                  float* __restrict__ out)
{
    const int s    = blockIdx.x;
    const int lane = threadIdx.x;
    const int g    = (lane < NG) ? lane : (NG - 1);   // clamp idle lanes

    __shared__ __align__(16) float x_lds[DIM];        // bf16-valued f32
    __shared__ __align__(16) float h_lds[NLAY][16];   // bf16-valued f32, [15]=0

    // ---- weights: bf16-cast once, f32 registers ----
    float wx[DIM];
    #pragma unroll
    for (int q = 0; q < DIM/4; ++q) {
        float4 w = *(const float4*)(Wih0 + g*DIM + 4*q);
        wx[4*q+0] = bfr(w.x); wx[4*q+1] = bfr(w.y);
        wx[4*q+2] = bfr(w.z); wx[4*q+3] = bfr(w.w);
    }
    float wr[NLAY][16];
    float wi[NLAY-1][16];
    float bias[NLAY];
    #pragma unroll
    for (int l = 0; l < NLAY; ++l) {
        #pragma unroll
        for (int j = 0; j < HID; ++j) wr[l][j] = bfr(Whh[(l*NG + g)*HID + j]);
        wr[l][15] = 0.0f;
        bias[l] = bfr(bfr(bih[l*NG + g]) + bfr(bhh[l*NG + g]));  // b = bih + bhh
    }
    #pragma unroll
    for (int l = 0; l < NLAY-1; ++l) {
        #pragma unroll
        for (int j = 0; j < HID; ++j) wi[l][j] = bfr(Wihr[(l*NG + g)*HID + j]);
        wi[l][15] = 0.0f;
    }

    if (lane < 16) {
        #pragma unroll
        for (int l = 0; l < NLAY; ++l) h_lds[l][lane] = 0.0f;
    }
    float c[NLAY] = {0.0f, 0.0f, 0.0f, 0.0f};

    int len = lengths[s];
    len = len < 1 ? 1 : (len > SEQT ? SEQT : len);
    const float* xb = emb + (size_t)s * SEQT * DIM;

    x_lds[lane] = bfr(xb[lane]);
    __syncthreads();

    const bool tanh_gate = (lane >= 30 && lane < 45);
    const float4* x4 = (const float4*)x_lds;

    float hout = 0.0f;

    for (int t = 0; t < len; ++t) {
        const int tn = (t + 1 < len) ? (t + 1) : t;
        const float xn = bfr(xb[(size_t)tn * DIM + lane]);   // prefetch next x

        #pragma unroll
        for (int l = 0; l < NLAY; ++l) {
            // ---- A1 = (x or h_{l-1}) . W_in : SEQUENTIAL bf16 accumulation,
            //      k ascending, round after every mul and every add (np generic matmul)
            float a_in = 0.0f;
            if (l == 0) {
                #pragma unroll
                for (int q = 0; q < 16; ++q) {
                    float4 v = x4[q];
                    CH(a_in, v.x, wx[4*q+0]);
                    CH(a_in, v.y, wx[4*q+1]);
                    CH(a_in, v.z, wx[4*q+2]);
                    CH(a_in, v.w, wx[4*q+3]);
                }
            } else {
                const float4* hp = (const float4*)h_lds[l-1];
                float hv[16];
                *(float4*)&hv[0]  = hp[0]; *(float4*)&hv[4]  = hp[1];
                *(float4*)&hv[8]  = hp[2]; *(float4*)&hv[12] = hp[3];
                #pragma unroll
                for (int j = 0; j < HID; ++j) CH(a_in, hv[j], wi[l-1][j]);
            }
            // ---- A2 = h_l . W_hh : same policy
            float a_rec = 0.0f;
            {
                const float4* hc = (const float4*)h_lds[l];
                float hv[16];
                *(float4*)&hv[0]  = hc[0]; *(float4*)&hv[4]  = hc[1];
                *(float4*)&hv[8]  = hc[2]; *(float4*)&hv[12] = hc[3];
                #pragma unroll
                for (int j = 0; j < HID; ++j) CH(a_rec, hv[j], wr[l][j]);
            }
            // g = (A1 + A2) + b, each add bf16-rounded (left-to-right)
            const float z = bfr(bfr(a_in + a_rec) + bias[l]);

            // per-lane activation (i,f,o: per-op sigmoid; g: single-round tanh)
            const float a = tanh_gate ? tanh_np(z) : sig_np(z);

            // gate combine: lane j<15 gathers f(j+15), g(j+30), o(j+45)
            const float fv = __shfl(a, (lane + 15) & 63);
            const float gv = __shfl(a, (lane + 30) & 63);
            const float ov = __shfl(a, (lane + 45) & 63);

            // c = bf(bf(f*c) + bf(i*g));  h = bf(o * tanh_np(c))
            const float cn = bfr(bfr(fv * c[l]) + bfr(a * gv));
            c[l] = cn;
            const float hn = bfr(ov * tanh_np(cn));

            if (lane < HID) h_lds[l][lane] = hn;   // in-order LDS within wave
            if (l == NLAY-1 && t == len-1) hout = hn;
        }

        x_lds[lane] = xn;   // after all x reads this iter (in-order per wave)
    }

    if (lane < HID) out[s * HID + lane] = hout;
}

extern "C" void kernel_launch(void* const* d_in, const int* in_sizes, int n_in,
                              void* d_out, int out_size, void* d_ws, size_t ws_size,
                              hipStream_t stream) {
    const float* emb     = (const float*)d_in[0];
    const int*   lengths = (const int*)  d_in[1];
    const float* Wih0    = (const float*)d_in[2];
    const float* Wihr    = (const float*)d_in[3];
    const float* Whh     = (const float*)d_in[4];
    const float* bih     = (const float*)d_in[5];
    const float* bhh     = (const float*)d_in[6];
    float* out = (float*)d_out;

    const int B = out_size / HID;   // 512
    lstm4_bf16np<<<B, 64, 0, stream>>>(emb, lengths, Wih0, Wihr, Whh, bih, bhh, out);
}

// Round 7
// 2395.578 us; speedup vs baseline: 3.0663x; 3.0663x over previous
//
#include <hip/hip_runtime.h>

#define HID 15
#define NG  60      // 4*HID
#define DIM 64
#define T2  2048
#define NLAY 4
#define BSZ 512

// Round-to-nearest-even bf16 quantization (bit ops — fast-math-proof).
__device__ __forceinline__ float bfr(float x) {
    unsigned u = __float_as_uint(x);
    u = (u + 0x7FFFu + ((u >> 16) & 1u)) & 0xFFFF0000u;
    return __uint_as_float(u);
}
// one bf16-rounded multiply-accumulate term: acc = bf(acc + bf(a*b))
#define CH(acc, a, b) acc = bfr(acc + bfr((a) * (b)))

__device__ __forceinline__ float tanh_np(float z) {
    const float e = __expf(-2.0f * z);
    return bfr((1.0f - e) / (1.0f + e));
}
__device__ __forceinline__ float sig_np(float z) {
    const float e   = bfr(__expf(-z));
    const float den = bfr(1.0f + e);
    return bfr(1.0f / den);
}
__device__ __forceinline__ float b2f(unsigned short b) {
    return __uint_as_float(((unsigned)b) << 16);
}

// ============ Phase 1: layer-0 input projection, fully parallel ============
// pa[r*NG+g] = sequential-bf16 chain over k of bf(x[r][k]*wx[g][k]) — exact
// same op order as the recurrent kernel used in round 6 → bit-identical.
__global__ __launch_bounds__(256, 1)
void proj0(const float* __restrict__ emb,
           const int*   __restrict__ lengths,
           const float* __restrict__ Wih0,
           unsigned short* __restrict__ pa)
{
    const int wave = threadIdx.x >> 6;
    const int lane = threadIdx.x & 63;
    const int g    = (lane < NG) ? lane : (NG - 1);

    __shared__ __align__(16) float xrow[4][64];

    float wx[DIM];
    #pragma unroll
    for (int q = 0; q < 16; ++q) {
        float4 w = *(const float4*)(Wih0 + g*DIM + 4*q);
        wx[4*q+0] = bfr(w.x); wx[4*q+1] = bfr(w.y);
        wx[4*q+2] = bfr(w.z); wx[4*q+3] = bfr(w.w);
    }

    const int nrows = BSZ * T2;
    for (int r = blockIdx.x * 4 + wave; r < nrows; r += gridDim.x * 4) {
        const int b = r >> 11;          // r / T2
        const int t = r & (T2 - 1);
        if (t >= lengths[b]) continue;  // row never consumed by recurrence

        xrow[wave][lane] = bfr(emb[(size_t)r * DIM + lane]);
        // in-wave ds_write -> ds_read: compiler inserts lgkmcnt wait
        const float4* xv = (const float4*)xrow[wave];
        float acc = 0.0f;
        #pragma unroll
        for (int q = 0; q < 16; ++q) {
            float4 v = xv[q];
            CH(acc, v.x, wx[4*q+0]);
            CH(acc, v.y, wx[4*q+1]);
            CH(acc, v.z, wx[4*q+2]);
            CH(acc, v.w, wx[4*q+3]);
        }
        if (lane < NG)
            pa[(size_t)r * NG + g] = (unsigned short)(__float_as_uint(acc) >> 16);
    }
}

// ============ Phase 2: 4-wave layer-pipelined recurrence ============
// Wave l computes layer l at t = k - l. h_l(t) handed to wave l+1 through
// h_lds[t&1][l]; one barrier per superstep orders write(k) vs overwrite(k+2).
// Own-layer h recurrence broadcast via readlane -> uniform scalars (SGPRs).
__global__ __launch_bounds__(256, 1)
void lstm4_pipe(const int* __restrict__ lengths,
                const unsigned short* __restrict__ pa,
                const float* __restrict__ Wihr,
                const float* __restrict__ Whh,
                const float* __restrict__ bih,
                const float* __restrict__ bhh,
                float* __restrict__ out)
{
    const int s    = blockIdx.x;
    const int wave = threadIdx.x >> 6;     // = layer index
    const int lane = threadIdx.x & 63;
    const int g    = (lane < NG) ? lane : (NG - 1);

    __shared__ __align__(16) float h_lds[2][NLAY][16];

    float wr[16], wi[16];
    #pragma unroll
    for (int j = 0; j < HID; ++j) wr[j] = bfr(Whh[(wave*NG + g)*HID + j]);
    wr[15] = 0.0f;
    if (wave > 0) {
        #pragma unroll
        for (int j = 0; j < HID; ++j) wi[j] = bfr(Wihr[((wave-1)*NG + g)*HID + j]);
        wi[15] = 0.0f;
    } else {
        #pragma unroll
        for (int j = 0; j < 16; ++j) wi[j] = 0.0f;
    }
    const float bias_ = bfr(bfr(bih[wave*NG + g]) + bfr(bhh[wave*NG + g]));

    int len = lengths[s];
    len = len < 1 ? 1 : (len > T2 ? T2 : len);
    const unsigned short* pas = pa + (size_t)s * T2 * NG;

    float c_ = 0.0f;
    float hs[HID];
    #pragma unroll
    for (int j = 0; j < HID; ++j) hs[j] = 0.0f;

    unsigned short panb = 0;
    if (wave == 0) panb = pas[g];          // a_in bits for t=0

    const bool tg = (lane >= 30 && lane < 45);

    for (int k = 0; k < len + NLAY - 1; ++k) {
        const int t = k - wave;
        if (t >= 0 && t < len) {           // wave-uniform predicate
            float a_in = 0.0f, a_rec = 0.0f;
            float hv[16];

            if (wave > 0) {                // issue LDS reads early
                const float4* hp = (const float4*)h_lds[t & 1][wave - 1];
                *(float4*)&hv[0]  = hp[0]; *(float4*)&hv[4]  = hp[1];
                *(float4*)&hv[8]  = hp[2]; *(float4*)&hv[12] = hp[3];
            }

            // a_rec: SGPR h × VGPR w — no memory dependence, fills LDS latency
            #pragma unroll
            for (int j = 0; j < HID; ++j) CH(a_rec, hs[j], wr[j]);

            if (wave == 0) {
                a_in = b2f(panb);          // loaded one superstep ago
                if (t + 1 < len) panb = pas[(size_t)(t + 1) * NG + g];
            } else {
                #pragma unroll
                for (int j = 0; j < HID; ++j) CH(a_in, hv[j], wi[j]);
            }

            const float z = bfr(bfr(a_in + a_rec) + bias_);
            const float a = tg ? tanh_np(z) : sig_np(z);

            const float fv = __shfl(a, (lane + 15) & 63);
            const float gv = __shfl(a, (lane + 30) & 63);
            const float ov = __shfl(a, (lane + 45) & 63);

            const float cn = bfr(bfr(fv * c_) + bfr(a * gv));
            c_ = cn;
            const float hn = bfr(ov * tanh_np(cn));

            #pragma unroll
            for (int j = 0; j < HID; ++j)
                hs[j] = __uint_as_float(__builtin_amdgcn_readlane(__float_as_uint(hn), j));

            if (lane < HID) h_lds[t & 1][wave][lane] = hn;
            if (wave == NLAY - 1 && t == len - 1 && lane < HID)
                out[s * HID + lane] = hn;
        }
        __syncthreads();
    }
}

// ============ Fallback (round-6, passing): used if ws too small ============
__global__ __launch_bounds__(64, 1)
void lstm4_bf16np(const float* __restrict__ emb,
                  const int*   __restrict__ lengths,
                  const float* __restrict__ Wih0,
                  const float* __restrict__ Wihr,
                  const float* __restrict__ Whh,
                  const float* __restrict__ bih,
                  const float* __restrict__ bhh,
                  float* __restrict__ out)
{
    const int s    = blockIdx.x;
    const int lane = threadIdx.x;
    const int g    = (lane < NG) ? lane : (NG - 1);

    __shared__ __align__(16) float x_lds[DIM];
    __shared__ __align__(16) float h_lds[NLAY][16];

    float wx[DIM];
    #pragma unroll
    for (int q = 0; q < DIM/4; ++q) {
        float4 w = *(const float4*)(Wih0 + g*DIM + 4*q);
        wx[4*q+0] = bfr(w.x); wx[4*q+1] = bfr(w.y);
        wx[4*q+2] = bfr(w.z); wx[4*q+3] = bfr(w.w);
    }
    float wr[NLAY][16]; float wi[NLAY-1][16]; float bias[NLAY];
    #pragma unroll
    for (int l = 0; l < NLAY; ++l) {
        #pragma unroll
        for (int j = 0; j < HID; ++j) wr[l][j] = bfr(Whh[(l*NG + g)*HID + j]);
        wr[l][15] = 0.0f;
        bias[l] = bfr(bfr(bih[l*NG + g]) + bfr(bhh[l*NG + g]));
    }
    #pragma unroll
    for (int l = 0; l < NLAY-1; ++l) {
        #pragma unroll
        for (int j = 0; j < HID; ++j) wi[l][j] = bfr(Wihr[(l*NG + g)*HID + j]);
        wi[l][15] = 0.0f;
    }
    if (lane < 16) {
        #pragma unroll
        for (int l = 0; l < NLAY; ++l) h_lds[l][lane] = 0.0f;
    }
    float c[NLAY] = {0.0f, 0.0f, 0.0f, 0.0f};
    int len = lengths[s];
    len = len < 1 ? 1 : (len > T2 ? T2 : len);
    const float* xb = emb + (size_t)s * T2 * DIM;
    x_lds[lane] = bfr(xb[lane]);
    __syncthreads();
    const bool tg = (lane >= 30 && lane < 45);
    const float4* x4 = (const float4*)x_lds;
    float hout = 0.0f;
    for (int t = 0; t < len; ++t) {
        const int tn = (t + 1 < len) ? (t + 1) : t;
        const float xn = bfr(xb[(size_t)tn * DIM + lane]);
        #pragma unroll
        for (int l = 0; l < NLAY; ++l) {
            float a_in = 0.0f;
            if (l == 0) {
                #pragma unroll
                for (int q = 0; q < 16; ++q) {
                    float4 v = x4[q];
                    CH(a_in, v.x, wx[4*q+0]); CH(a_in, v.y, wx[4*q+1]);
                    CH(a_in, v.z, wx[4*q+2]); CH(a_in, v.w, wx[4*q+3]);
                }
            } else {
                const float4* hp = (const float4*)h_lds[l-1];
                float hv[16];
                *(float4*)&hv[0]  = hp[0]; *(float4*)&hv[4]  = hp[1];
                *(float4*)&hv[8]  = hp[2]; *(float4*)&hv[12] = hp[3];
                #pragma unroll
                for (int j = 0; j < HID; ++j) CH(a_in, hv[j], wi[l-1][j]);
            }
            float a_rec = 0.0f;
            {
                const float4* hc = (const float4*)h_lds[l];
                float hv[16];
                *(float4*)&hv[0]  = hc[0]; *(float4*)&hv[4]  = hc[1];
                *(float4*)&hv[8]  = hc[2]; *(float4*)&hv[12] = hc[3];
                #pragma unroll
                for (int j = 0; j < HID; ++j) CH(a_rec, hv[j], wr[l][j]);
            }
            const float z = bfr(bfr(a_in + a_rec) + bias[l]);
            const float a = tg ? tanh_np(z) : sig_np(z);
            const float fv = __shfl(a, (lane + 15) & 63);
            const float gv = __shfl(a, (lane + 30) & 63);
            const float ov = __shfl(a, (lane + 45) & 63);
            const float cn = bfr(bfr(fv * c[l]) + bfr(a * gv));
            c[l] = cn;
            const float hn = bfr(ov * tanh_np(cn));
            if (lane < HID) h_lds[l][lane] = hn;
            if (l == NLAY-1 && t == len-1) hout = hn;
        }
        x_lds[lane] = xn;
    }
    if (lane < HID) out[s * HID + lane] = hout;
}

extern "C" void kernel_launch(void* const* d_in, const int* in_sizes, int n_in,
                              void* d_out, int out_size, void* d_ws, size_t ws_size,
                              hipStream_t stream) {
    const float* emb     = (const float*)d_in[0];
    const int*   lengths = (const int*)  d_in[1];
    const float* Wih0    = (const float*)d_in[2];
    const float* Wihr    = (const float*)d_in[3];
    const float* Whh     = (const float*)d_in[4];
    const float* bih     = (const float*)d_in[5];
    const float* bhh     = (const float*)d_in[6];
    float* out = (float*)d_out;

    const size_t need = (size_t)BSZ * T2 * NG * sizeof(unsigned short);
    if (ws_size >= need) {
        unsigned short* pa = (unsigned short*)d_ws;
        proj0<<<2048, 256, 0, stream>>>(emb, lengths, Wih0, pa);
        lstm4_pipe<<<BSZ, 256, 0, stream>>>(lengths, pa, Wihr, Whh, bih, bhh, out);
    } else {
        lstm4_bf16np<<<BSZ, 64, 0, stream>>>(emb, lengths, Wih0, Wihr, Whh, bih, bhh, out);
    }
}